// Round 1
// baseline (359.271 us; speedup 1.0000x reference)
//
#include <hip/hip_runtime.h>
#include <stdint.h>

typedef __attribute__((ext_vector_type(8))) short bf16x8;
typedef __attribute__((ext_vector_type(4))) float f32x4;

#define IMG 222

__device__ __forceinline__ unsigned short f2bf(float f){
  unsigned int u = __float_as_uint(f);
  unsigned int r = (u + 0x7fffu + ((u >> 16) & 1u)) >> 16;
  return (unsigned short)r;
}

// Transpose + bf16-cast the weight matrices once per launch.
// qwt[n][k] = qkv_w[k][n]  (n<384, k<128)
// pwt[n][k] = proj_w[k][n] (n<128, k<128)
__global__ void prep_weights(const float* __restrict__ qkv_w,
                             const float* __restrict__ proj_w,
                             unsigned short* __restrict__ qwt,
                             unsigned short* __restrict__ pwt){
  int i = blockIdx.x * blockDim.x + threadIdx.x;
  if (i < 384*128){ int n = i >> 7, k = i & 127; qwt[i] = f2bf(qkv_w[k*384 + n]); }
  if (i < 128*128){ int n = i >> 7, k = i & 127; pwt[i] = f2bf(proj_w[k*128 + n]); }
}

__global__ __launch_bounds__(256, 2)
void win_attn(const float* __restrict__ x,
              const float* __restrict__ qkv_b,
              const float* __restrict__ proj_b,
              const unsigned short* __restrict__ qwt,
              const unsigned short* __restrict__ pwt,
              float* __restrict__ out)
{
  // LDS layout (ushort units):
  //  [0,8192)      xs  [64][128]   (A for qkv GEMM)     -- later ps overlay
  //  [8192,16384)  qs  [64][128]                         -- later ps overlay
  //  [16384,24576) ksm [64][128]                         -- later osm overlay
  //  [24576,32768) vst [128][64]   (v transposed)
  //  ps = [4 heads][64][64] at offset 0 (32KB overlay of xs+qs)
  //  osm = [64][128] at 16384 (overlay of ksm)
  extern __shared__ unsigned short lds[];
  unsigned short* xs  = lds;
  unsigned short* qs  = lds + 8192;
  unsigned short* ksm = lds + 16384;
  unsigned short* vst = lds + 24576;
  unsigned short* ps  = lds;
  unsigned short* osm = lds + 16384;

  const int tid = threadIdx.x;
  const int wid = tid >> 6;
  const int l   = tid & 63;
  const int l15 = l & 15;
  const int lhi = l >> 4;

  const int w  = blockIdx.x;       // window id
  const int b  = w >> 10;
  const int wi = (w >> 5) & 31;
  const int wj = w & 31;

  // ---- phase 0: stage x window -> xs (bf16), zeros for pad tokens ----
  {
    const int t  = tid >> 2;            // token 0..63
    const int cb = (tid & 3) * 32;      // channel base
    const int r  = t / 7, c = t - r*7;
    const int gh = wi*7 + r, gw = wj*7 + c;
    const bool valid = (t < 49) && (gh < IMG) && (gw < IMG);
    const float* src = x + (((size_t)((size_t)b*IMG + gh))*IMG + gw)*128 + cb;
    unsigned short* dst = xs + t*128 + cb;
    #pragma unroll
    for (int i = 0; i < 8; ++i){
      float4 v = valid ? *(const float4*)(src + i*4) : make_float4(0.f,0.f,0.f,0.f);
      dst[i*4+0] = f2bf(v.x); dst[i*4+1] = f2bf(v.y);
      dst[i*4+2] = f2bf(v.z); dst[i*4+3] = f2bf(v.w);
    }
  }
  __syncthreads();

  // ---- phase 1: qkv GEMM  [64x128]@[128x384] ----
  bf16x8 a[4][4];
  #pragma unroll
  for (int mi = 0; mi < 4; ++mi)
    #pragma unroll
    for (int ks = 0; ks < 4; ++ks)
      a[mi][ks] = *(const bf16x8*)(xs + (mi*16 + l15)*128 + ks*32 + lhi*8);

  const float scale = 0.17677669529663687f;   // 32^-0.5

  #pragma unroll
  for (int nj = 0; nj < 6; ++nj){
    const int ni = wid + nj*4;               // n-tile 0..23
    bf16x8 bfr[4];
    #pragma unroll
    for (int ks = 0; ks < 4; ++ks)
      bfr[ks] = *(const bf16x8*)(qwt + (ni*16 + l15)*128 + ks*32 + lhi*8);
    const float bias = qkv_b[ni*16 + l15];
    #pragma unroll
    for (int mi = 0; mi < 4; ++mi){
      f32x4 acc = {0.f,0.f,0.f,0.f};
      #pragma unroll
      for (int ks = 0; ks < 4; ++ks)
        acc = __builtin_amdgcn_mfma_f32_16x16x32_bf16(a[mi][ks], bfr[ks], acc, 0, 0, 0);
      #pragma unroll
      for (int r = 0; r < 4; ++r){
        float val = acc[r] + bias;
        int row = mi*16 + lhi*4 + r;          // token
        int col = ni*16 + l15;                // channel in [0,384)
        if (ni < 8){
          qs[row*128 + col] = f2bf(val * scale);
        } else if (ni < 16){
          ksm[row*128 + (col - 128)] = f2bf(val);
        } else {
          vst[(col - 256)*64 + row] = f2bf(val);
        }
      }
    }
  }
  __syncthreads();

  // ---- phase 2: S = q @ k^T per head (wave = head) ----
  const int h = wid;
  f32x4 sacc[4][4];
  {
    bf16x8 aq[4], bk[4];
    #pragma unroll
    for (int i = 0; i < 4; ++i){
      aq[i] = *(const bf16x8*)(qs  + (i*16 + l15)*128 + h*32 + lhi*8);
      bk[i] = *(const bf16x8*)(ksm + (i*16 + l15)*128 + h*32 + lhi*8);
    }
    #pragma unroll
    for (int mi = 0; mi < 4; ++mi)
      #pragma unroll
      for (int ni = 0; ni < 4; ++ni){
        f32x4 z = {0.f,0.f,0.f,0.f};
        sacc[mi][ni] = __builtin_amdgcn_mfma_f32_16x16x32_bf16(aq[mi], bk[ni], z, 0, 0, 0);
      }
  }
  __syncthreads();   // everyone done reading qs/ksm; overlays become writable

  // ---- softmax (rows of 49 valid cols; cols 49..63 masked) ----
  if (l15 > 0){
    #pragma unroll
    for (int mi = 0; mi < 4; ++mi)
      #pragma unroll
      for (int r = 0; r < 4; ++r)
        sacc[mi][3][r] = -1e30f;              // cols 48+l15 >= 49
  }
  #pragma unroll
  for (int mi = 0; mi < 4; ++mi){
    #pragma unroll
    for (int r = 0; r < 4; ++r){
      float m = fmaxf(fmaxf(sacc[mi][0][r], sacc[mi][1][r]),
                      fmaxf(sacc[mi][2][r], sacc[mi][3][r]));
      m = fmaxf(m, __shfl_xor(m, 1));
      m = fmaxf(m, __shfl_xor(m, 2));
      m = fmaxf(m, __shfl_xor(m, 4));
      m = fmaxf(m, __shfl_xor(m, 8));
      float e0 = __expf(sacc[mi][0][r] - m);
      float e1 = __expf(sacc[mi][1][r] - m);
      float e2 = __expf(sacc[mi][2][r] - m);
      float e3 = __expf(sacc[mi][3][r] - m);
      float s = e0 + e1 + e2 + e3;
      s += __shfl_xor(s, 1); s += __shfl_xor(s, 2);
      s += __shfl_xor(s, 4); s += __shfl_xor(s, 8);
      float inv = 1.0f / s;
      int row = mi*16 + lhi*4 + r;
      unsigned short* pr = ps + h*4096 + row*64 + l15;
      pr[0]  = f2bf(e0*inv);
      pr[16] = f2bf(e1*inv);
      pr[32] = f2bf(e2*inv);
      pr[48] = f2bf(e3*inv);
    }
  }

  // ---- phase 3: O = P @ v_h  (M=64,N=32,K=64) ----
  f32x4 oacc[4][2];
  {
    bf16x8 pa[4][2], bv[2][2];
    #pragma unroll
    for (int mi = 0; mi < 4; ++mi)
      #pragma unroll
      for (int ks = 0; ks < 2; ++ks)
        pa[mi][ks] = *(const bf16x8*)(ps + h*4096 + (mi*16 + l15)*64 + ks*32 + lhi*8);
    #pragma unroll
    for (int ni = 0; ni < 2; ++ni)
      #pragma unroll
      for (int ks = 0; ks < 2; ++ks)
        bv[ni][ks] = *(const bf16x8*)(vst + (h*32 + ni*16 + l15)*64 + ks*32 + lhi*8);
    #pragma unroll
    for (int mi = 0; mi < 4; ++mi)
      #pragma unroll
      for (int ni = 0; ni < 2; ++ni){
        f32x4 acc = {0.f,0.f,0.f,0.f};
        acc = __builtin_amdgcn_mfma_f32_16x16x32_bf16(pa[mi][0], bv[ni][0], acc, 0, 0, 0);
        acc = __builtin_amdgcn_mfma_f32_16x16x32_bf16(pa[mi][1], bv[ni][1], acc, 0, 0, 0);
        oacc[mi][ni] = acc;
      }
  }
  #pragma unroll
  for (int mi = 0; mi < 4; ++mi)
    #pragma unroll
    for (int ni = 0; ni < 2; ++ni)
      #pragma unroll
      for (int r = 0; r < 4; ++r)
        osm[(mi*16 + lhi*4 + r)*128 + h*32 + ni*16 + l15] = f2bf(oacc[mi][ni][r]);
  __syncthreads();

  // ---- phase 4: proj GEMM [64x128]@[128x128] + bias + scatter ----
  bf16x8 ao[4][4];
  #pragma unroll
  for (int mi = 0; mi < 4; ++mi)
    #pragma unroll
    for (int ks = 0; ks < 4; ++ks)
      ao[mi][ks] = *(const bf16x8*)(osm + (mi*16 + l15)*128 + ks*32 + lhi*8);

  #pragma unroll
  for (int nj = 0; nj < 2; ++nj){
    const int ni = wid + nj*4;               // n-tile 0..7
    bf16x8 pb[4];
    #pragma unroll
    for (int ks = 0; ks < 4; ++ks)
      pb[ks] = *(const bf16x8*)(pwt + (ni*16 + l15)*128 + ks*32 + lhi*8);
    const float bias = proj_b[ni*16 + l15];
    #pragma unroll
    for (int mi = 0; mi < 4; ++mi){
      f32x4 acc = {0.f,0.f,0.f,0.f};
      #pragma unroll
      for (int ks = 0; ks < 4; ++ks)
        acc = __builtin_amdgcn_mfma_f32_16x16x32_bf16(ao[mi][ks], pb[ks], acc, 0, 0, 0);
      #pragma unroll
      for (int r = 0; r < 4; ++r){
        int t = mi*16 + lhi*4 + r;
        if (t < 49){
          int rr = t / 7, cc = t - rr*7;
          int gh = wi*7 + rr, gw = wj*7 + cc;
          if (gh < IMG && gw < IMG)
            out[(((size_t)((size_t)b*IMG + gh))*IMG + gw)*128 + ni*16 + l15] = acc[r] + bias;
        }
      }
    }
  }
}

extern "C" void kernel_launch(void* const* d_in, const int* in_sizes, int n_in,
                              void* d_out, int out_size, void* d_ws, size_t ws_size,
                              hipStream_t stream) {
  const float* x      = (const float*)d_in[0];
  const float* qkv_w  = (const float*)d_in[1];
  const float* qkv_b  = (const float*)d_in[2];
  const float* proj_w = (const float*)d_in[3];
  const float* proj_b = (const float*)d_in[4];
  float* out = (float*)d_out;

  unsigned short* qwt = (unsigned short*)d_ws;          // 384*128 bf16
  unsigned short* pwt = qwt + 384*128;                  // 128*128 bf16

  hipLaunchKernelGGL(prep_weights, dim3(192), dim3(256), 0, stream,
                     qkv_w, proj_w, qwt, pwt);
  hipLaunchKernelGGL(win_attn, dim3(8192), dim3(256), 65536, stream,
                     x, qkv_b, proj_b, qwt, pwt, out);
}

// Round 2
// 256.141 us; speedup vs baseline: 1.4026x; 1.4026x over previous
//
#include <hip/hip_runtime.h>
#include <stdint.h>

typedef __attribute__((ext_vector_type(8))) short bf16x8;
typedef __attribute__((ext_vector_type(4))) float f32x4;

#define IMG 222

__device__ __forceinline__ unsigned short f2bf(float f){
  unsigned int u = __float_as_uint(f);
  return (unsigned short)((u + 0x7fffu + ((u >> 16) & 1u)) >> 16);
}

// XOR bank swizzles (ushort units). Involution: applied on write AND read.
__device__ __forceinline__ int sw128(int r, int c){ return r*128 + (c ^ ((r & 7) << 3)); }
__device__ __forceinline__ int sw64 (int r, int c){ return r*64  + (c ^ ((r & 7) << 3)); }

// Transpose + bf16-cast the weight matrices once per launch.
__global__ void prep_weights(const float* __restrict__ qkv_w,
                             const float* __restrict__ proj_w,
                             unsigned short* __restrict__ qwt,
                             unsigned short* __restrict__ pwt){
  int i = blockIdx.x * blockDim.x + threadIdx.x;
  if (i < 384*128){ int n = i >> 7, k = i & 127; qwt[i] = f2bf(qkv_w[k*384 + n]); }
  if (i < 128*128){ int n = i >> 7, k = i & 127; pwt[i] = f2bf(proj_w[k*128 + n]); }
}

__global__ __launch_bounds__(256, 3)
void win_attn(const float* __restrict__ x,
              const float* __restrict__ qkv_b,
              const float* __restrict__ proj_b,
              const unsigned short* __restrict__ qwt,
              const unsigned short* __restrict__ pwt,
              float* __restrict__ out)
{
  // LDS 48KB, three 16KB regions (ushort units), overlaid across phases:
  //  r0 [0,8192)      : xs[64][128]  -> qs[64][128]   -> ps heads 0,1
  //  r1 [8192,16384)  : ksm[64][128]                  -> ps heads 2,3
  //  r2 [16384,24576) : vst[128][64]                  -> osm[64][128]
  // All tiles XOR-swizzled (sw128/sw64).
  extern __shared__ unsigned short lds[];
  unsigned short* r0 = lds;
  unsigned short* r1 = lds + 8192;
  unsigned short* r2 = lds + 16384;

  const int tid = threadIdx.x;
  const int wid = tid >> 6;
  const int l   = tid & 63;
  const int l15 = l & 15;
  const int lhi = l >> 4;

  const int w  = blockIdx.x;       // window id
  const int b  = w >> 10;
  const int wi = (w >> 5) & 31;
  const int wj = w & 31;

  // ---- phase 0: stage x window -> r0 (bf16, swizzled), zeros for pad ----
  {
    const int t  = tid >> 2;            // token 0..63
    const int cb = (tid & 3) * 32;      // channel base
    const int r  = t / 7, c = t - r*7;
    const int gh = wi*7 + r, gw = wj*7 + c;
    const bool valid = (t < 49) && (gh < IMG) && (gw < IMG);
    const float* src = x + (((size_t)((size_t)b*IMG + gh))*IMG + gw)*128 + cb;
    #pragma unroll
    for (int i = 0; i < 8; ++i){
      float4 v = valid ? *(const float4*)(src + i*4) : make_float4(0.f,0.f,0.f,0.f);
      unsigned short* dst = r0 + sw128(t, cb + i*4);   // 4 consecutive ushorts stay contiguous
      dst[0] = f2bf(v.x); dst[1] = f2bf(v.y); dst[2] = f2bf(v.z); dst[3] = f2bf(v.w);
    }
  }
  __syncthreads();

  // ---- load A fragments for qkv GEMM into registers ----
  bf16x8 a[4][4];
  #pragma unroll
  for (int mi = 0; mi < 4; ++mi)
    #pragma unroll
    for (int ks = 0; ks < 4; ++ks)
      a[mi][ks] = *(const bf16x8*)(r0 + sw128(mi*16 + l15, ks*32 + lhi*8));
  __syncthreads();   // xs fully consumed; r0 becomes q destination

  const float scale = 0.17677669529663687f;   // 32^-0.5

  // ---- phase 1: qkv GEMM  [64x128]@[128x384] ----
  #pragma unroll
  for (int nj = 0; nj < 6; ++nj){
    const int ni = wid + nj*4;               // n-tile 0..23
    bf16x8 bfr[4];
    #pragma unroll
    for (int ks = 0; ks < 4; ++ks)
      bfr[ks] = *(const bf16x8*)(qwt + (ni*16 + l15)*128 + ks*32 + lhi*8);
    const float bias = qkv_b[ni*16 + l15];
    #pragma unroll
    for (int mi = 0; mi < 4; ++mi){
      f32x4 acc = {0.f,0.f,0.f,0.f};
      #pragma unroll
      for (int ks = 0; ks < 4; ++ks)
        acc = __builtin_amdgcn_mfma_f32_16x16x32_bf16(a[mi][ks], bfr[ks], acc, 0, 0, 0);
      #pragma unroll
      for (int r = 0; r < 4; ++r){
        float val = acc[r] + bias;
        int row = mi*16 + lhi*4 + r;          // token
        int col = ni*16 + l15;                // channel in [0,384)
        if (ni < 8){
          r0[sw128(row, col)] = f2bf(val * scale);          // q (scaled)
        } else if (ni < 16){
          r1[sw128(row, col - 128)] = f2bf(val);            // k
        } else {
          r2[sw64(col - 256, row)] = f2bf(val);             // v transposed
        }
      }
    }
  }
  __syncthreads();

  // ---- phase 2: S = q @ k^T per head (wave = head) ----
  const int h = wid;
  f32x4 sacc[4][4];
  {
    bf16x8 aq[4], bk[4];
    #pragma unroll
    for (int i = 0; i < 4; ++i){
      aq[i] = *(const bf16x8*)(r0 + sw128(i*16 + l15, h*32 + lhi*8));
      bk[i] = *(const bf16x8*)(r1 + sw128(i*16 + l15, h*32 + lhi*8));
    }
    #pragma unroll
    for (int mi = 0; mi < 4; ++mi)
      #pragma unroll
      for (int ni = 0; ni < 4; ++ni){
        f32x4 z = {0.f,0.f,0.f,0.f};
        sacc[mi][ni] = __builtin_amdgcn_mfma_f32_16x16x32_bf16(aq[mi], bk[ni], z, 0, 0, 0);
      }
  }
  __syncthreads();   // q,k dead; r0+r1 become ps = [4 heads][64][64]

  // ---- softmax (rows of 49 valid cols; cols 49..63 masked) ----
  unsigned short* pb = lds + h*4096;          // this head's swizzled [64][64] P tile
  if (l15 > 0){
    #pragma unroll
    for (int mi = 0; mi < 4; ++mi)
      #pragma unroll
      for (int r = 0; r < 4; ++r)
        sacc[mi][3][r] = -1e30f;              // cols 48+l15 >= 49
  }
  #pragma unroll
  for (int mi = 0; mi < 4; ++mi){
    #pragma unroll
    for (int r = 0; r < 4; ++r){
      float m = fmaxf(fmaxf(sacc[mi][0][r], sacc[mi][1][r]),
                      fmaxf(sacc[mi][2][r], sacc[mi][3][r]));
      m = fmaxf(m, __shfl_xor(m, 1));
      m = fmaxf(m, __shfl_xor(m, 2));
      m = fmaxf(m, __shfl_xor(m, 4));
      m = fmaxf(m, __shfl_xor(m, 8));
      float e0 = __expf(sacc[mi][0][r] - m);
      float e1 = __expf(sacc[mi][1][r] - m);
      float e2 = __expf(sacc[mi][2][r] - m);
      float e3 = __expf(sacc[mi][3][r] - m);
      float s = e0 + e1 + e2 + e3;
      s += __shfl_xor(s, 1); s += __shfl_xor(s, 2);
      s += __shfl_xor(s, 4); s += __shfl_xor(s, 8);
      float inv = 1.0f / s;
      int row = mi*16 + lhi*4 + r;
      pb[sw64(row, l15)]      = f2bf(e0*inv);
      pb[sw64(row, l15 + 16)] = f2bf(e1*inv);
      pb[sw64(row, l15 + 32)] = f2bf(e2*inv);
      pb[sw64(row, l15 + 48)] = f2bf(e3*inv);
    }
  }

  // ---- phase 3: O = P @ v_h  (M=64,N=32,K=64) ----
  bf16x8 pa[4][2], bv[2][2];
  #pragma unroll
  for (int mi = 0; mi < 4; ++mi)
    #pragma unroll
    for (int ks = 0; ks < 2; ++ks)
      pa[mi][ks] = *(const bf16x8*)(pb + sw64(mi*16 + l15, ks*32 + lhi*8));
  #pragma unroll
  for (int ni = 0; ni < 2; ++ni)
    #pragma unroll
    for (int ks = 0; ks < 2; ++ks)
      bv[ni][ks] = *(const bf16x8*)(r2 + sw64(h*32 + ni*16 + l15, ks*32 + lhi*8));
  __syncthreads();   // all waves hold their v fragments; r2 becomes osm

  f32x4 oacc[4][2];
  #pragma unroll
  for (int mi = 0; mi < 4; ++mi)
    #pragma unroll
    for (int ni = 0; ni < 2; ++ni){
      f32x4 acc = {0.f,0.f,0.f,0.f};
      acc = __builtin_amdgcn_mfma_f32_16x16x32_bf16(pa[mi][0], bv[ni][0], acc, 0, 0, 0);
      acc = __builtin_amdgcn_mfma_f32_16x16x32_bf16(pa[mi][1], bv[ni][1], acc, 0, 0, 0);
      oacc[mi][ni] = acc;
    }
  #pragma unroll
  for (int mi = 0; mi < 4; ++mi)
    #pragma unroll
    for (int ni = 0; ni < 2; ++ni)
      #pragma unroll
      for (int r = 0; r < 4; ++r)
        r2[sw128(mi*16 + lhi*4 + r, h*32 + ni*16 + l15)] = f2bf(oacc[mi][ni][r]);
  __syncthreads();

  // ---- phase 4: proj GEMM [64x128]@[128x128] + bias + scatter ----
  bf16x8 ao[4][4];
  #pragma unroll
  for (int mi = 0; mi < 4; ++mi)
    #pragma unroll
    for (int ks = 0; ks < 4; ++ks)
      ao[mi][ks] = *(const bf16x8*)(r2 + sw128(mi*16 + l15, ks*32 + lhi*8));

  #pragma unroll
  for (int nj = 0; nj < 2; ++nj){
    const int ni = wid + nj*4;               // n-tile 0..7
    bf16x8 pbw[4];
    #pragma unroll
    for (int ks = 0; ks < 4; ++ks)
      pbw[ks] = *(const bf16x8*)(pwt + (ni*16 + l15)*128 + ks*32 + lhi*8);
    const float bias = proj_b[ni*16 + l15];
    #pragma unroll
    for (int mi = 0; mi < 4; ++mi){
      f32x4 acc = {0.f,0.f,0.f,0.f};
      #pragma unroll
      for (int ks = 0; ks < 4; ++ks)
        acc = __builtin_amdgcn_mfma_f32_16x16x32_bf16(ao[mi][ks], pbw[ks], acc, 0, 0, 0);
      #pragma unroll
      for (int r = 0; r < 4; ++r){
        int t = mi*16 + lhi*4 + r;
        if (t < 49){
          int rr = t / 7, cc = t - rr*7;
          int gh = wi*7 + rr, gw = wj*7 + cc;
          if (gh < IMG && gw < IMG)
            out[(((size_t)((size_t)b*IMG + gh))*IMG + gw)*128 + ni*16 + l15] = acc[r] + bias;
        }
      }
    }
  }
}

extern "C" void kernel_launch(void* const* d_in, const int* in_sizes, int n_in,
                              void* d_out, int out_size, void* d_ws, size_t ws_size,
                              hipStream_t stream) {
  const float* x      = (const float*)d_in[0];
  const float* qkv_w  = (const float*)d_in[1];
  const float* qkv_b  = (const float*)d_in[2];
  const float* proj_w = (const float*)d_in[3];
  const float* proj_b = (const float*)d_in[4];
  float* out = (float*)d_out;

  unsigned short* qwt = (unsigned short*)d_ws;          // 384*128 bf16
  unsigned short* pwt = qwt + 384*128;                  // 128*128 bf16

  hipLaunchKernelGGL(prep_weights, dim3(192), dim3(256), 0, stream,
                     qkv_w, proj_w, qwt, pwt);
  hipLaunchKernelGGL(win_attn, dim3(8192), dim3(256), 49152, stream,
                     x, qkv_b, proj_b, qwt, pwt, out);
}

// Round 3
// 215.282 us; speedup vs baseline: 1.6688x; 1.1898x over previous
//
#include <hip/hip_runtime.h>
#include <stdint.h>

typedef __attribute__((ext_vector_type(8))) short bf16x8;
typedef __attribute__((ext_vector_type(4))) float f32x4;

#define IMG 222

__device__ __forceinline__ unsigned short f2bf(float f){
  unsigned int u = __float_as_uint(f);
  return (unsigned short)((u + 0x7fffu + ((u >> 16) & 1u)) >> 16);
}

// XOR bank swizzles (ushort units). Involution: applied on write AND read.
__device__ __forceinline__ int sw128(int r, int c){ return r*128 + (c ^ ((r & 7) << 3)); }
__device__ __forceinline__ int sw64 (int r, int c){ return r*64  + (c ^ ((r & 7) << 3)); }

// Transpose + bf16-cast the weight matrices once per launch.
__global__ void prep_weights(const float* __restrict__ qkv_w,
                             const float* __restrict__ proj_w,
                             unsigned short* __restrict__ qwt,
                             unsigned short* __restrict__ pwt){
  int i = blockIdx.x * blockDim.x + threadIdx.x;
  if (i < 384*128){ int n = i >> 7, k = i & 127; qwt[i] = f2bf(qkv_w[k*384 + n]); }
  if (i < 128*128){ int n = i >> 7, k = i & 127; pwt[i] = f2bf(proj_w[k*128 + n]); }
}

__global__ __launch_bounds__(256, 3)
void win_attn(const float* __restrict__ x,
              const float* __restrict__ qkv_b,
              const float* __restrict__ proj_b,
              const unsigned short* __restrict__ qwt,
              const unsigned short* __restrict__ pwt,
              float* __restrict__ out)
{
  // LDS 48KB, three 16KB regions (ushort units), overlaid across phases:
  //  r0 [0,8192)      : xs[64][128] -> qs[64][128] -> P heads 0,1
  //  r1 [8192,16384)  : ksm[64][128]               -> P heads 2,3
  //  r2 [16384,24576) : vst[128][64]               -> osm[64][128]
  extern __shared__ unsigned short lds[];
  unsigned short* r0 = lds;
  unsigned short* r1 = lds + 8192;
  unsigned short* r2 = lds + 16384;

  const int tid = threadIdx.x;
  const int wid = tid >> 6;
  const int l   = tid & 63;
  const int l15 = l & 15;
  const int lhi = l >> 4;

  // XCD-aware block swizzle: 8192 blocks = 8 XCDs x 1024 contiguous windows.
  const int w  = (blockIdx.x & 7) * 1024 + (blockIdx.x >> 3);
  const int b  = w >> 10;
  const int wi = (w >> 5) & 31;
  const int wj = w & 31;

  // ---- phase 0: stage x window -> r0 (bf16, swizzled, b64-packed) ----
  {
    const int t  = tid >> 2;            // token 0..63
    const int cb = (tid & 3) * 32;      // channel base
    const int r  = t / 7, c = t - r*7;
    const int gh = wi*7 + r, gw = wj*7 + c;
    const bool valid = (t < 49) && (gh < IMG) && (gw < IMG);
    const float* src = x + (((size_t)((size_t)b*IMG + gh))*IMG + gw)*128 + cb;
    #pragma unroll
    for (int i = 0; i < 8; ++i){
      float4 v = valid ? *(const float4*)(src + i*4) : make_float4(0.f,0.f,0.f,0.f);
      *(ushort4*)(r0 + sw128(t, cb + i*4)) =
        make_ushort4(f2bf(v.x), f2bf(v.y), f2bf(v.z), f2bf(v.w));
    }
  }
  __syncthreads();

  // ---- load x A/B fragments into registers, then free r0 for q ----
  bf16x8 a[4][4];
  #pragma unroll
  for (int mi = 0; mi < 4; ++mi)
    #pragma unroll
    for (int ks = 0; ks < 4; ++ks)
      a[mi][ks] = *(const bf16x8*)(r0 + sw128(mi*16 + l15, ks*32 + lhi*8));
  __syncthreads();

  const float scale = 0.17677669529663687f;   // 32^-0.5

  // ---- phase 1: qkv GEMM  [64x128]@[128x384] ----
  #pragma unroll
  for (int nj = 0; nj < 6; ++nj){
    const int ni = wid + nj*4;               // n-tile 0..23
    bf16x8 bfr[4];
    #pragma unroll
    for (int ks = 0; ks < 4; ++ks)
      bfr[ks] = *(const bf16x8*)(qwt + (ni*16 + l15)*128 + ks*32 + lhi*8);
    if (nj < 4){
      // q (nj<2) / k (nj 2,3): swapped mfma -> col=token(l15), regs=4 consecutive channels
      const float4 bias4 = *(const float4*)(qkv_b + ni*16 + lhi*4);
      #pragma unroll
      for (int mi = 0; mi < 4; ++mi){
        f32x4 acc = {0.f,0.f,0.f,0.f};
        #pragma unroll
        for (int ks = 0; ks < 4; ++ks)
          acc = __builtin_amdgcn_mfma_f32_16x16x32_bf16(bfr[ks], a[mi][ks], acc, 0, 0, 0);
        if (nj < 2){
          *(ushort4*)(r0 + sw128(mi*16 + l15, ni*16 + lhi*4)) =
            make_ushort4(f2bf((acc[0]+bias4.x)*scale), f2bf((acc[1]+bias4.y)*scale),
                         f2bf((acc[2]+bias4.z)*scale), f2bf((acc[3]+bias4.w)*scale));
        } else {
          *(ushort4*)(r1 + sw128(mi*16 + l15, (ni-8)*16 + lhi*4)) =
            make_ushort4(f2bf(acc[0]+bias4.x), f2bf(acc[1]+bias4.y),
                         f2bf(acc[2]+bias4.z), f2bf(acc[3]+bias4.w));
        }
      }
    } else {
      // v: normal mfma -> col=channel(l15), regs=4 consecutive tokens -> vst[ch][tok]
      const float bias = qkv_b[ni*16 + l15];
      #pragma unroll
      for (int mi = 0; mi < 4; ++mi){
        f32x4 acc = {0.f,0.f,0.f,0.f};
        #pragma unroll
        for (int ks = 0; ks < 4; ++ks)
          acc = __builtin_amdgcn_mfma_f32_16x16x32_bf16(a[mi][ks], bfr[ks], acc, 0, 0, 0);
        *(ushort4*)(r2 + sw64((ni-16)*16 + l15, mi*16 + lhi*4)) =
          make_ushort4(f2bf(acc[0]+bias), f2bf(acc[1]+bias),
                       f2bf(acc[2]+bias), f2bf(acc[3]+bias));
      }
    }
  }
  __syncthreads();

  // ---- phase 2: S^T = K·Q^T per head (wave = head), softmax over k ----
  const int h = wid;
  unsigned short* ph = lds + h*4096;          // this head's P~ [64 q][64 k] (swizzled)
  bf16x8 aq[4], bk[4];
  #pragma unroll
  for (int i = 0; i < 4; ++i){
    aq[i] = *(const bf16x8*)(r0 + sw128(i*16 + l15, h*32 + lhi*8));
    bk[i] = *(const bf16x8*)(r1 + sw128(i*16 + l15, h*32 + lhi*8));
  }
  __syncthreads();   // all q/k reads done; r0+r1 become P~ regions

  float invs[4];
  #pragma unroll
  for (int mi = 0; mi < 4; ++mi){
    // S^T tile: col=l15=q-token (mi*16+l15), row=k = ni*16 + lhi*4 + r
    f32x4 st[4];
    #pragma unroll
    for (int ni = 0; ni < 4; ++ni){
      f32x4 z = {0.f,0.f,0.f,0.f};
      st[ni] = __builtin_amdgcn_mfma_f32_16x16x32_bf16(bk[ni], aq[mi], z, 0, 0, 0);
    }
    // mask k >= 49 (ni==3: k = 48 + lhi*4 + r; only lhi==0,r==0 valid)
    st[3][1] = -1e30f; st[3][2] = -1e30f; st[3][3] = -1e30f;
    if (lhi != 0) st[3][0] = -1e30f;
    float m = st[0][0];
    #pragma unroll
    for (int ni = 0; ni < 4; ++ni)
      #pragma unroll
      for (int r = 0; r < 4; ++r)
        m = fmaxf(m, st[ni][r]);
    m = fmaxf(m, __shfl_xor(m, 16));
    m = fmaxf(m, __shfl_xor(m, 32));
    float e[4][4], s = 0.f;
    #pragma unroll
    for (int ni = 0; ni < 4; ++ni)
      #pragma unroll
      for (int r = 0; r < 4; ++r){
        e[ni][r] = __expf(st[ni][r] - m);
        s += e[ni][r];
      }
    s += __shfl_xor(s, 16);
    s += __shfl_xor(s, 32);
    invs[mi] = __builtin_amdgcn_rcpf(s);      // normalize deferred to O
    #pragma unroll
    for (int ni = 0; ni < 4; ++ni)
      *(ushort4*)(ph + sw64(mi*16 + l15, ni*16 + lhi*4)) =
        make_ushort4(f2bf(e[ni][0]), f2bf(e[ni][1]), f2bf(e[ni][2]), f2bf(e[ni][3]));
  }

  // ---- phase 3: O^T = V^T · P~^T  (swapped mfma) ----
  bf16x8 pa[4][2], bv[2][2];
  #pragma unroll
  for (int mi = 0; mi < 4; ++mi)
    #pragma unroll
    for (int ks = 0; ks < 2; ++ks)
      pa[mi][ks] = *(const bf16x8*)(ph + sw64(mi*16 + l15, ks*32 + lhi*8));
  #pragma unroll
  for (int nc = 0; nc < 2; ++nc)
    #pragma unroll
    for (int ks = 0; ks < 2; ++ks)
      bv[nc][ks] = *(const bf16x8*)(r2 + sw64(h*32 + nc*16 + l15, ks*32 + lhi*8));
  __syncthreads();   // v reads done; r2 becomes osm [64 tok][128 ch]

  #pragma unroll
  for (int mi = 0; mi < 4; ++mi){
    const float is = invs[mi];
    #pragma unroll
    for (int nc = 0; nc < 2; ++nc){
      f32x4 acc = {0.f,0.f,0.f,0.f};
      acc = __builtin_amdgcn_mfma_f32_16x16x32_bf16(bv[nc][0], pa[mi][0], acc, 0, 0, 0);
      acc = __builtin_amdgcn_mfma_f32_16x16x32_bf16(bv[nc][1], pa[mi][1], acc, 0, 0, 0);
      // col=l15=token(mi*16+l15), regs = 4 consecutive channels
      *(ushort4*)(r2 + sw128(mi*16 + l15, h*32 + nc*16 + lhi*4)) =
        make_ushort4(f2bf(acc[0]*is), f2bf(acc[1]*is), f2bf(acc[2]*is), f2bf(acc[3]*is));
    }
  }
  __syncthreads();

  // ---- phase 4: proj GEMM (swapped) + bias + float4 scatter ----
  bf16x8 ao[4][4];
  #pragma unroll
  for (int mi = 0; mi < 4; ++mi)
    #pragma unroll
    for (int ks = 0; ks < 4; ++ks)
      ao[mi][ks] = *(const bf16x8*)(r2 + sw128(mi*16 + l15, ks*32 + lhi*8));

  #pragma unroll
  for (int nj = 0; nj < 2; ++nj){
    const int ni = wid + nj*4;               // out-channel tile 0..7
    bf16x8 pbw[4];
    #pragma unroll
    for (int ks = 0; ks < 4; ++ks)
      pbw[ks] = *(const bf16x8*)(pwt + (ni*16 + l15)*128 + ks*32 + lhi*8);
    const float4 bias4 = *(const float4*)(proj_b + ni*16 + lhi*4);
    #pragma unroll
    for (int mi = 0; mi < 4; ++mi){
      f32x4 acc = {0.f,0.f,0.f,0.f};
      #pragma unroll
      for (int ks = 0; ks < 4; ++ks)
        acc = __builtin_amdgcn_mfma_f32_16x16x32_bf16(pbw[ks], ao[mi][ks], acc, 0, 0, 0);
      const int t = mi*16 + l15;             // token (per-lane uniform across regs)
      if (t < 49){
        const int rr = t / 7, cc = t - rr*7;
        const int gh = wi*7 + rr, gw = wj*7 + cc;
        if (gh < IMG && gw < IMG){
          float4 o = make_float4(acc[0]+bias4.x, acc[1]+bias4.y,
                                 acc[2]+bias4.z, acc[3]+bias4.w);
          *(float4*)(out + (((size_t)((size_t)b*IMG + gh))*IMG + gw)*128 + ni*16 + lhi*4) = o;
        }
      }
    }
  }
}

extern "C" void kernel_launch(void* const* d_in, const int* in_sizes, int n_in,
                              void* d_out, int out_size, void* d_ws, size_t ws_size,
                              hipStream_t stream) {
  const float* x      = (const float*)d_in[0];
  const float* qkv_w  = (const float*)d_in[1];
  const float* qkv_b  = (const float*)d_in[2];
  const float* proj_w = (const float*)d_in[3];
  const float* proj_b = (const float*)d_in[4];
  float* out = (float*)d_out;

  unsigned short* qwt = (unsigned short*)d_ws;          // 384*128 bf16
  unsigned short* pwt = qwt + 384*128;                  // 128*128 bf16

  hipLaunchKernelGGL(prep_weights, dim3(192), dim3(256), 0, stream,
                     qkv_w, proj_w, qwt, pwt);
  hipLaunchKernelGGL(win_attn, dim3(8192), dim3(256), 49152, stream,
                     x, qkv_b, proj_b, qwt, pwt, out);
}

// Round 4
// 207.262 us; speedup vs baseline: 1.7334x; 1.0387x over previous
//
#include <hip/hip_runtime.h>
#include <stdint.h>

typedef __attribute__((ext_vector_type(8))) short bf16x8;
typedef __attribute__((ext_vector_type(4))) float f32x4;
typedef __attribute__((ext_vector_type(4))) unsigned int u32x4;

#define IMG 222

__device__ __forceinline__ unsigned short f2bf(float f){
  unsigned int u = __float_as_uint(f);
  return (unsigned short)((u + 0x7fffu + ((u >> 16) & 1u)) >> 16);
}

// HW packed f32->bf16 (RNE): lo -> D[15:0], hi -> D[31:16]
__device__ __forceinline__ unsigned int pk2bf(float lo, float hi){
  unsigned int r;
  asm("v_cvt_pk_bf16_f32 %0, %1, %2" : "=v"(r) : "v"(lo), "v"(hi));
  return r;
}

// XOR bank swizzles (ushort units). Involution: applied on write AND read.
__device__ __forceinline__ int sw128(int r, int c){ return r*128 + (c ^ ((r & 7) << 3)); }
__device__ __forceinline__ int sw64 (int r, int c){ return r*64  + (c ^ ((r & 7) << 3)); }

// Transpose + bf16-cast the weight matrices once per launch.
__global__ void prep_weights(const float* __restrict__ qkv_w,
                             const float* __restrict__ proj_w,
                             unsigned short* __restrict__ qwt,
                             unsigned short* __restrict__ pwt){
  int i = blockIdx.x * blockDim.x + threadIdx.x;
  if (i < 384*128){ int n = i >> 7, k = i & 127; qwt[i] = f2bf(qkv_w[k*384 + n]); }
  if (i < 128*128){ int n = i >> 7, k = i & 127; pwt[i] = f2bf(proj_w[k*128 + n]); }
}

__global__ __launch_bounds__(256, 4)
void win_attn(const float* __restrict__ x,
              const float* __restrict__ qkv_b,
              const float* __restrict__ proj_b,
              const unsigned short* __restrict__ qwt,
              const unsigned short* __restrict__ pwt,
              float* __restrict__ out)
{
  // LDS 40KB (ushort units):
  //  r0 [0,8192)      : xs[64][128] -> q[64][128] -> P heads 0,1 -> osm[64][128]
  //  r1 [8192,16384)  : k[64][128]                -> P heads 2,3
  //  r2 [16384,20480) : vhalf [4 heads][16 ch][64 tok]  (ch 16..31 of each head)
  // v ch 0..15 of each head lives in the producing wave's registers.
  extern __shared__ unsigned short lds[];
  unsigned short* r0 = lds;
  unsigned short* r1 = lds + 8192;
  unsigned short* r2 = lds + 16384;

  const int tid = threadIdx.x;
  const int wid = tid >> 6;
  const int l   = tid & 63;
  const int l15 = l & 15;
  const int lhi = l >> 4;

  // XCD-aware block swizzle: 8192 blocks = 8 XCDs x 1024 contiguous windows.
  const int w  = (blockIdx.x & 7) * 1024 + (blockIdx.x >> 3);
  const int b  = w >> 10;
  const int wi = (w >> 5) & 31;
  const int wj = w & 31;

  // ---- phase 0: stage x window -> r0 (bf16, swizzled, b64-packed) ----
  {
    const int t  = tid >> 2;            // token 0..63
    const int cb = (tid & 3) * 32;      // channel base
    const int r  = t / 7, c = t - r*7;
    const int gh = wi*7 + r, gw = wj*7 + c;
    const bool valid = (t < 49) && (gh < IMG) && (gw < IMG);
    const float* src = x + (((size_t)((size_t)b*IMG + gh))*IMG + gw)*128 + cb;
    #pragma unroll
    for (int i = 0; i < 8; ++i){
      float4 v = valid ? *(const float4*)(src + i*4) : make_float4(0.f,0.f,0.f,0.f);
      uint2 pk; pk.x = pk2bf(v.x, v.y); pk.y = pk2bf(v.z, v.w);
      *(uint2*)(r0 + sw128(t, cb + i*4)) = pk;
    }
  }
  __syncthreads();

  // ---- load x A/B fragments into registers, then free r0 for q ----
  bf16x8 a[4][4];
  #pragma unroll
  for (int mi = 0; mi < 4; ++mi)
    #pragma unroll
    for (int ks = 0; ks < 4; ++ks)
      a[mi][ks] = *(const bf16x8*)(r0 + sw128(mi*16 + l15, ks*32 + lhi*8));
  __syncthreads();

  const float scale = 0.17677669529663687f;   // 32^-0.5

  // ---- phase 1a: q,k tiles (swapped mfma: col=token, regs=4 consecutive ch) ----
  #pragma unroll
  for (int s = 0; s < 4; ++s){
    const int nt = wid + s*4;               // tiles 0..15: q (nt<8), k (nt>=8)
    bf16x8 bfr[4];
    #pragma unroll
    for (int ks = 0; ks < 4; ++ks)
      bfr[ks] = *(const bf16x8*)(qwt + (nt*16 + l15)*128 + ks*32 + lhi*8);
    const float4 bias4 = *(const float4*)(qkv_b + nt*16 + lhi*4);
    #pragma unroll
    for (int mi = 0; mi < 4; ++mi){
      f32x4 acc = {0.f,0.f,0.f,0.f};
      #pragma unroll
      for (int ks = 0; ks < 4; ++ks)
        acc = __builtin_amdgcn_mfma_f32_16x16x32_bf16(bfr[ks], a[mi][ks], acc, 0, 0, 0);
      uint2 pk;
      if (s < 2){
        pk.x = pk2bf((acc[0]+bias4.x)*scale, (acc[1]+bias4.y)*scale);
        pk.y = pk2bf((acc[2]+bias4.z)*scale, (acc[3]+bias4.w)*scale);
        *(uint2*)(r0 + sw128(mi*16 + l15, nt*16 + lhi*4)) = pk;
      } else {
        pk.x = pk2bf(acc[0]+bias4.x, acc[1]+bias4.y);
        pk.y = pk2bf(acc[2]+bias4.z, acc[3]+bias4.w);
        *(uint2*)(r1 + sw128(mi*16 + l15, (nt-8)*16 + lhi*4)) = pk;
      }
    }
  }

  // ---- phase 1b: v tiles for OWN head (normal mfma: col=ch, regs=4 tokens) ----
  unsigned int pkv[4][2];                    // v ch 0..15 of head wid, packed bf16
  {
    const int nt0 = 16 + 2*wid;              // ch 32h .. 32h+15
    bf16x8 bfr[4];
    #pragma unroll
    for (int ks = 0; ks < 4; ++ks)
      bfr[ks] = *(const bf16x8*)(qwt + (nt0*16 + l15)*128 + ks*32 + lhi*8);
    const float bias = qkv_b[nt0*16 + l15];
    #pragma unroll
    for (int mi = 0; mi < 4; ++mi){
      f32x4 acc = {0.f,0.f,0.f,0.f};
      #pragma unroll
      for (int ks = 0; ks < 4; ++ks)
        acc = __builtin_amdgcn_mfma_f32_16x16x32_bf16(a[mi][ks], bfr[ks], acc, 0, 0, 0);
      pkv[mi][0] = pk2bf(acc[0]+bias, acc[1]+bias);   // tokens mi*16+lhi*4 +0,+1
      pkv[mi][1] = pk2bf(acc[2]+bias, acc[3]+bias);   // tokens +2,+3
    }
  }
  {
    const int nt1 = 17 + 2*wid;              // ch 32h+16 .. 32h+31 -> LDS r2
    bf16x8 bfr[4];
    #pragma unroll
    for (int ks = 0; ks < 4; ++ks)
      bfr[ks] = *(const bf16x8*)(qwt + (nt1*16 + l15)*128 + ks*32 + lhi*8);
    const float bias = qkv_b[nt1*16 + l15];
    unsigned short* vh = r2 + wid*1024;      // [16 ch][64 tok] swizzled
    #pragma unroll
    for (int mi = 0; mi < 4; ++mi){
      f32x4 acc = {0.f,0.f,0.f,0.f};
      #pragma unroll
      for (int ks = 0; ks < 4; ++ks)
        acc = __builtin_amdgcn_mfma_f32_16x16x32_bf16(a[mi][ks], bfr[ks], acc, 0, 0, 0);
      uint2 pk;
      pk.x = pk2bf(acc[0]+bias, acc[1]+bias);
      pk.y = pk2bf(acc[2]+bias, acc[3]+bias);
      *(uint2*)(vh + sw64(l15, mi*16 + lhi*4)) = pk;
    }
  }
  __syncthreads();

  // ---- phase 2: S^T = K·Q^T per head (wave = head), softmax over k ----
  const int h = wid;
  unsigned short* ph = lds + h*4096;          // this head's P~ [64 q][64 k] (swizzled)
  bf16x8 aq[4], bk[4];
  #pragma unroll
  for (int i = 0; i < 4; ++i){
    aq[i] = *(const bf16x8*)(r0 + sw128(i*16 + l15, h*32 + lhi*8));
    bk[i] = *(const bf16x8*)(r1 + sw128(i*16 + l15, h*32 + lhi*8));
  }
  __syncthreads();   // all q/k reads done; r0+r1 become P~ regions

  float invs[4];
  #pragma unroll
  for (int mi = 0; mi < 4; ++mi){
    // S^T tile: col=l15=q-token (mi*16+l15), row=k = ni*16 + lhi*4 + r
    f32x4 st[4];
    #pragma unroll
    for (int ni = 0; ni < 4; ++ni){
      f32x4 z = {0.f,0.f,0.f,0.f};
      st[ni] = __builtin_amdgcn_mfma_f32_16x16x32_bf16(bk[ni], aq[mi], z, 0, 0, 0);
    }
    // mask k >= 49 (ni==3: k = 48 + lhi*4 + r; only lhi==0,r==0 valid)
    st[3][1] = -1e30f; st[3][2] = -1e30f; st[3][3] = -1e30f;
    if (lhi != 0) st[3][0] = -1e30f;
    float m = st[0][0];
    #pragma unroll
    for (int ni = 0; ni < 4; ++ni)
      #pragma unroll
      for (int r = 0; r < 4; ++r)
        m = fmaxf(m, st[ni][r]);
    m = fmaxf(m, __shfl_xor(m, 16));
    m = fmaxf(m, __shfl_xor(m, 32));
    float e[4][4], s = 0.f;
    #pragma unroll
    for (int ni = 0; ni < 4; ++ni)
      #pragma unroll
      for (int r = 0; r < 4; ++r){
        e[ni][r] = __expf(st[ni][r] - m);
        s += e[ni][r];
      }
    s += __shfl_xor(s, 16);
    s += __shfl_xor(s, 32);
    invs[mi] = __builtin_amdgcn_rcpf(s);      // normalize deferred to O
    #pragma unroll
    for (int ni = 0; ni < 4; ++ni){
      uint2 pk;
      pk.x = pk2bf(e[ni][0], e[ni][1]);
      pk.y = pk2bf(e[ni][2], e[ni][3]);
      *(uint2*)(ph + sw64(mi*16 + l15, ni*16 + lhi*4)) = pk;
    }
  }

  // ---- phase 3 prep: load P / v-half fragments; rebuild v ch0..15 frags ----
  bf16x8 pa[4][2];
  #pragma unroll
  for (int mi = 0; mi < 4; ++mi)
    #pragma unroll
    for (int ks = 0; ks < 2; ++ks)
      pa[mi][ks] = *(const bf16x8*)(ph + sw64(mi*16 + l15, ks*32 + lhi*8));
  bf16x8 bv1[2];
  {
    unsigned short* vh = r2 + wid*1024;
    #pragma unroll
    for (int ks = 0; ks < 2; ++ks)
      bv1[ks] = *(const bf16x8*)(vh + sw64(l15, ks*32 + lhi*8));
  }
  // bv0 from pkv: target lane (lhi) token group ks*32+lhi*8+2jj(+1):
  //   src tile mi = 2ks + (lhi>>1), src lane lhi_src = 2*(lhi&1) + (jj>>1), word p = jj&1
  bf16x8 bv0[2];
  {
    const int srcA = ((l & 16) << 1) + l15;   // 2*(lhi&1)*16 + l15
    #pragma unroll
    for (int ks = 0; ks < 2; ++ks){
      u32x4 wv;
      #pragma unroll
      for (int jj = 0; jj < 4; ++jj){
        const int src = srcA + ((jj >> 1) << 4);
        unsigned int va = (unsigned int)__shfl((int)pkv[2*ks][jj & 1], src);
        unsigned int vb = (unsigned int)__shfl((int)pkv[2*ks+1][jj & 1], src);
        wv[jj] = (lhi & 2) ? vb : va;
      }
      bv0[ks] = __builtin_bit_cast(bf16x8, wv);
    }
  }
  __syncthreads();   // P/v reads done; r0 becomes osm [64 tok][128 ch]

  // ---- phase 3: O^T = V^T · P~^T  (swapped mfma) ----
  #pragma unroll
  for (int mi = 0; mi < 4; ++mi){
    const float is = invs[mi];
    #pragma unroll
    for (int nc = 0; nc < 2; ++nc){
      f32x4 acc = {0.f,0.f,0.f,0.f};
      acc = __builtin_amdgcn_mfma_f32_16x16x32_bf16(nc ? bv1[0] : bv0[0], pa[mi][0], acc, 0, 0, 0);
      acc = __builtin_amdgcn_mfma_f32_16x16x32_bf16(nc ? bv1[1] : bv0[1], pa[mi][1], acc, 0, 0, 0);
      uint2 pk;
      pk.x = pk2bf(acc[0]*is, acc[1]*is);
      pk.y = pk2bf(acc[2]*is, acc[3]*is);
      *(uint2*)(r0 + sw128(mi*16 + l15, h*32 + nc*16 + lhi*4)) = pk;
    }
  }
  __syncthreads();

  // ---- phase 4: proj GEMM (swapped) + bias + float4 scatter ----
  bf16x8 ao[4][4];
  #pragma unroll
  for (int mi = 0; mi < 4; ++mi)
    #pragma unroll
    for (int ks = 0; ks < 4; ++ks)
      ao[mi][ks] = *(const bf16x8*)(r0 + sw128(mi*16 + l15, ks*32 + lhi*8));

  #pragma unroll
  for (int nj = 0; nj < 2; ++nj){
    const int ni = wid + nj*4;               // out-channel tile 0..7
    bf16x8 pbw[4];
    #pragma unroll
    for (int ks = 0; ks < 4; ++ks)
      pbw[ks] = *(const bf16x8*)(pwt + (ni*16 + l15)*128 + ks*32 + lhi*8);
    const float4 bias4 = *(const float4*)(proj_b + ni*16 + lhi*4);
    #pragma unroll
    for (int mi = 0; mi < 4; ++mi){
      f32x4 acc = {0.f,0.f,0.f,0.f};
      #pragma unroll
      for (int ks = 0; ks < 4; ++ks)
        acc = __builtin_amdgcn_mfma_f32_16x16x32_bf16(pbw[ks], ao[mi][ks], acc, 0, 0, 0);
      const int t = mi*16 + l15;             // token (per-lane uniform across regs)
      if (t < 49){
        const int rr = t / 7, cc = t - rr*7;
        const int gh = wi*7 + rr, gw = wj*7 + cc;
        if (gh < IMG && gw < IMG){
          float4 o = make_float4(acc[0]+bias4.x, acc[1]+bias4.y,
                                 acc[2]+bias4.z, acc[3]+bias4.w);
          *(float4*)(out + (((size_t)((size_t)b*IMG + gh))*IMG + gw)*128 + ni*16 + lhi*4) = o;
        }
      }
    }
  }
}

extern "C" void kernel_launch(void* const* d_in, const int* in_sizes, int n_in,
                              void* d_out, int out_size, void* d_ws, size_t ws_size,
                              hipStream_t stream) {
  const float* x      = (const float*)d_in[0];
  const float* qkv_w  = (const float*)d_in[1];
  const float* qkv_b  = (const float*)d_in[2];
  const float* proj_w = (const float*)d_in[3];
  const float* proj_b = (const float*)d_in[4];
  float* out = (float*)d_out;

  unsigned short* qwt = (unsigned short*)d_ws;          // 384*128 bf16
  unsigned short* pwt = qwt + 384*128;                  // 128*128 bf16

  hipLaunchKernelGGL(prep_weights, dim3(192), dim3(256), 0, stream,
                     qkv_w, proj_w, qwt, pwt);
  hipLaunchKernelGGL(win_attn, dim3(8192), dim3(256), 40960, stream,
                     x, qkv_b, proj_b, qwt, pwt, out);
}